// Round 2
// baseline (276.738 us; speedup 1.0000x reference)
//
#include <hip/hip_runtime.h>
#include <hip/hip_bf16.h>
#include <stdint.h>

#define Bn 4
#define Cn 64
#define Fn 50000
#define Kn 16
#define NTOT (Bn*Fn)
#define EPS 1e-5f

typedef unsigned short u16;
typedef unsigned int u32;

__device__ __forceinline__ u16 f2bf(float x) {
  __hip_bfloat16 h = __float2bfloat16(x);
  return *reinterpret_cast<u16*>(&h);
}
__device__ __forceinline__ u32 pack2(float a, float b) {
  return (u32)f2bf(a) | ((u32)f2bf(b) << 16);
}

// K1: Gt[(b*4+seg)][f][16ch] (bf16) = W(seg rows) x fea[b][:, f]
// grid (391, 4), 256 thr. Thread = (seg = t>>6, facepair fl = t&63):
// 16 channels x 2 faces => 64 B contiguous store per thread.
__global__ __launch_bounds__(256) void k1_wgemm(
    const float* __restrict__ fea, const float* __restrict__ W,
    u32* __restrict__ Gt) {
  const int b = blockIdx.y;
  const int f0 = blockIdx.x * 128;
  __shared__ float a_s[64][132];   // [c][f]
  __shared__ float w_s[64][68];    // [c][o]
  const int t = threadIdx.x;
  {
    const float4* W4 = (const float4*)W;  // 1024 float4
    #pragma unroll
    for (int jj = 0; jj < 4; ++jj) {
      int l = jj * 256 + t;
      float4 v = W4[l];
      int o = l >> 4;
      int c = (l & 15) << 2;
      w_s[c][o] = v.x; w_s[c+1][o] = v.y; w_s[c+2][o] = v.z; w_s[c+3][o] = v.w;
    }
  }
  {
    const float* fb = fea + ((size_t)b * Cn) * Fn + f0;
    #pragma unroll
    for (int jj = 0; jj < 8; ++jj) {
      int l = jj * 256 + t;        // float4 idx in 64c x 128f tile
      int c = l >> 5;
      int fi = (l & 31) << 2;
      float4 v = make_float4(0.f, 0.f, 0.f, 0.f);
      if (f0 + fi < Fn) v = *(const float4*)(fb + (size_t)c * Fn + fi);
      *(float4*)&a_s[c][fi] = v;
    }
  }
  __syncthreads();
  const int sg = t >> 6;      // wave-uniform seg
  const int fl = t & 63;      // face pair
  float acc[2][16];
  #pragma unroll
  for (int j = 0; j < 2; j++)
    #pragma unroll
    for (int i = 0; i < 16; i++) acc[j][i] = 0.f;
  const int o0 = sg << 4;
  #pragma unroll 4
  for (int c = 0; c < 64; c++) {
    float4 w0 = *(float4*)&w_s[c][o0];       // wave-uniform addr: broadcast
    float4 w1 = *(float4*)&w_s[c][o0 + 4];
    float4 w2 = *(float4*)&w_s[c][o0 + 8];
    float4 w3 = *(float4*)&w_s[c][o0 + 12];
    float2 av = *(float2*)&a_s[c][fl << 1];
    float wv[16] = {w0.x,w0.y,w0.z,w0.w, w1.x,w1.y,w1.z,w1.w,
                    w2.x,w2.y,w2.z,w2.w, w3.x,w3.y,w3.z,w3.w};
    #pragma unroll
    for (int i = 0; i < 16; i++) {
      acc[0][i] = fmaf(av.x, wv[i], acc[0][i]);
      acc[1][i] = fmaf(av.y, wv[i], acc[1][i]);
    }
  }
  // store: face rows of 16 bf16 (32 B) each, thread covers 2 faces = 64 B
  u32* gdst = Gt + ((size_t)(b * 4 + sg) * Fn + f0 + (fl << 1)) * 8;
  #pragma unroll
  for (int j = 0; j < 2; j++) {
    int f = f0 + (fl << 1) + j;
    if (f < Fn) {
      uint4 u0, u1;
      u0.x = pack2(acc[j][0], acc[j][1]);   u0.y = pack2(acc[j][2], acc[j][3]);
      u0.z = pack2(acc[j][4], acc[j][5]);   u0.w = pack2(acc[j][6], acc[j][7]);
      u1.x = pack2(acc[j][8], acc[j][9]);   u1.y = pack2(acc[j][10], acc[j][11]);
      u1.z = pack2(acc[j][12], acc[j][13]); u1.w = pack2(acc[j][14], acc[j][15]);
      *(uint4*)(gdst + (size_t)j * 8) = u0;
      *(uint4*)(gdst + (size_t)j * 8 + 4) = u1;
    }
  }
}

// K2: block = one (b, seg) combo x 512 faces. Gather 32 B rows from the
// (b,seg) slice of Gt (1.6 MB — L2 resident; bid%8 keeps combos c,c+8 on
// one XCD => 3.2 MB/XCD). Thread: 2 faces x 16 channels.
__global__ __launch_bounds__(256) void k2_gather(
    const u32* __restrict__ Gt, const int* __restrict__ ring,
    const float* __restrict__ bias, float* __restrict__ out,
    float* __restrict__ gsum, float* __restrict__ gsum2) {
  const int bid = blockIdx.x;
  const int combo = bid & 15;         // XCD = bid%8 = combo%8
  const int ft = bid >> 4;
  const int b = combo >> 2;
  const int seg = combo & 3;
  const int t = threadIdx.x;
  const int fa = ft * 512 + (t << 1); // even
  const bool valid = fa < Fn;         // fa+1 < Fn too (Fn even)

  __shared__ float bias_s[16];
  __shared__ float rs[4][16];
  __shared__ float rs2[4][16];
  if (t < 16) bias_s[t] = bias[seg * 16 + t];
  __syncthreads();

  float acc[2][16];
  #pragma unroll
  for (int j = 0; j < 2; j++)
    #pragma unroll
    for (int i = 0; i < 16; i++) acc[j][i] = 0.f;

  if (valid) {
    const uint4* Gs = (const uint4*)(Gt + (size_t)(b * 4 + seg) * Fn * 8);
    const int4* ra = (const int4*)(ring + ((size_t)b * Fn + fa) * Kn);
    const int4* rb = ra + 4;
    #pragma unroll
    for (int kc = 0; kc < 4; kc++) {
      int4 ia = ra[kc];
      int4 ib = rb[kc];
      int ja[4] = {ia.x, ia.y, ia.z, ia.w};
      int jb[4] = {ib.x, ib.y, ib.z, ib.w};
      #pragma unroll
      for (int m = 0; m < 4; m++) {
        uint4 g0 = Gs[(size_t)ja[m] * 2];
        uint4 g1 = Gs[(size_t)ja[m] * 2 + 1];
        uint4 h0 = Gs[(size_t)jb[m] * 2];
        uint4 h1 = Gs[(size_t)jb[m] * 2 + 1];
        u32 ga[8] = {g0.x,g0.y,g0.z,g0.w, g1.x,g1.y,g1.z,g1.w};
        u32 gb[8] = {h0.x,h0.y,h0.z,h0.w, h1.x,h1.y,h1.z,h1.w};
        #pragma unroll
        for (int p = 0; p < 8; p++) {
          acc[0][2*p]   += __uint_as_float(ga[p] << 16);
          acc[0][2*p+1] += __uint_as_float(ga[p] & 0xffff0000u);
          acc[1][2*p]   += __uint_as_float(gb[p] << 16);
          acc[1][2*p+1] += __uint_as_float(gb[p] & 0xffff0000u);
        }
      }
    }
    #pragma unroll
    for (int i = 0; i < 16; i++) {
      acc[0][i] += bias_s[i];
      acc[1][i] += bias_s[i];
    }
    // store fp32 y: per channel, lanes sweep consecutive face pairs (float2)
    float* ob = out + ((size_t)b * Cn + seg * 16) * Fn + fa;
    #pragma unroll
    for (int i = 0; i < 16; i++) {
      *(float2*)(ob + (size_t)i * Fn) = make_float2(acc[0][i], acc[1][i]);
    }
  }
  // per-channel stats: butterfly over the wave, then cross-wave via LDS
  const int w = t >> 6, lane = t & 63;
  #pragma unroll
  for (int i = 0; i < 16; i++) {
    float s  = acc[0][i] + acc[1][i];
    float s2 = acc[0][i]*acc[0][i] + acc[1][i]*acc[1][i];
    #pragma unroll
    for (int off = 32; off > 0; off >>= 1) {
      s  += __shfl_down(s, off);
      s2 += __shfl_down(s2, off);
    }
    if (lane == 0) { rs[w][i] = s; rs2[w][i] = s2; }
  }
  __syncthreads();
  if (t < 16) {
    atomicAdd(&gsum[seg * 16 + t], rs[0][t] + rs[1][t] + rs[2][t] + rs[3][t]);
  } else if (t < 32) {
    int i = t - 16;
    atomicAdd(&gsum2[seg * 16 + i], rs2[0][i] + rs2[1][i] + rs2[2][i] + rs2[3][i]);
  }
}

__global__ void k3_stats(const float* __restrict__ gsum, const float* __restrict__ gsum2,
                         const float* __restrict__ gamma, const float* __restrict__ beta,
                         float* __restrict__ ab) {
  int o = threadIdx.x;
  if (o < 64) {
    float inv = 1.0f / (float)NTOT;
    float mean = gsum[o] * inv;
    float var = gsum2[o] * inv - mean * mean;  // biased
    float r = rsqrtf(var + EPS);
    float a = gamma[o] * r;
    ab[o] = a;
    ab[64 + o] = beta[o] - mean * a;
  }
}

__global__ __launch_bounds__(256) void k4_norm(float* __restrict__ out,
                                               const float* __restrict__ ab) {
  int i = blockIdx.x * 256 + threadIdx.x;     // float4 index, exact cover
  int o = (i / (Fn / 4)) & 63;
  float a = ab[o], c = ab[64 + o];
  float4 v = ((float4*)out)[i];
  v.x = fmaxf(fmaf(v.x, a, c), 0.f);
  v.y = fmaxf(fmaf(v.y, a, c), 0.f);
  v.z = fmaxf(fmaf(v.z, a, c), 0.f);
  v.w = fmaxf(fmaf(v.w, a, c), 0.f);
  ((float4*)out)[i] = v;
}

extern "C" void kernel_launch(void* const* d_in, const int* in_sizes, int n_in,
                              void* d_out, int out_size, void* d_ws, size_t ws_size,
                              hipStream_t stream) {
  const float* fea   = (const float*)d_in[0];
  const int*   ring  = (const int*)d_in[1];
  const float* W     = (const float*)d_in[2];
  const float* bias  = (const float*)d_in[3];
  const float* gamma = (const float*)d_in[4];
  const float* beta  = (const float*)d_in[5];
  float* out = (float*)d_out;

  u32* Gt = (u32*)d_ws;                               // [B*4][Fn][16ch] bf16 = 25.6 MB
  const size_t statsOff = (size_t)Bn * Fn * 64 * 2;   // bytes
  float* gsum  = (float*)((char*)d_ws + statsOff);
  float* gsum2 = gsum + 64;
  float* ab    = gsum + 128;

  hipMemsetAsync(gsum, 0, 2 * 64 * sizeof(float), stream);
  k1_wgemm<<<dim3((Fn + 127) / 128, Bn), 256, 0, stream>>>(fea, W, Gt);
  const int ftiles = (Fn + 511) / 512;                // 98
  k2_gather<<<dim3(ftiles * 16), 256, 0, stream>>>(Gt, ring, bias, out, gsum, gsum2);
  k3_stats<<<1, 64, 0, stream>>>(gsum, gsum2, gamma, beta, ab);
  k4_norm<<<dim3((Bn * Cn * Fn / 4) / 256), 256, 0, stream>>>(out, ab);
}

// Round 3
// 211.364 us; speedup vs baseline: 1.3093x; 1.3093x over previous
//
#include <hip/hip_runtime.h>
#include <hip/hip_bf16.h>
#include <stdint.h>

#define Bn 4
#define Cn 64
#define Fn 50000
#define Kn 16
#define NTOT (Bn*Fn)
#define EPS 1e-5f

typedef unsigned short u16;
typedef unsigned int u32;

__device__ __forceinline__ u16 f2bf(float x) {
  __hip_bfloat16 h = __float2bfloat16(x);
  return *reinterpret_cast<u16*>(&h);
}
__device__ __forceinline__ u32 pack2(float a, float b) {
  return (u32)f2bf(a) | ((u32)f2bf(b) << 16);
}

// K1: Gt[(b*4+seg)][f][16ch] (bf16) = W(seg rows) x fea[b][:, f]
__global__ __launch_bounds__(256) void k1_wgemm(
    const float* __restrict__ fea, const float* __restrict__ W,
    u32* __restrict__ Gt) {
  const int b = blockIdx.y;
  const int f0 = blockIdx.x * 128;
  __shared__ float a_s[64][132];   // [c][f]
  __shared__ float w_s[64][68];    // [c][o]
  const int t = threadIdx.x;
  {
    const float4* W4 = (const float4*)W;  // 1024 float4
    #pragma unroll
    for (int jj = 0; jj < 4; ++jj) {
      int l = jj * 256 + t;
      float4 v = W4[l];
      int o = l >> 4;
      int c = (l & 15) << 2;
      w_s[c][o] = v.x; w_s[c+1][o] = v.y; w_s[c+2][o] = v.z; w_s[c+3][o] = v.w;
    }
  }
  {
    const float* fb = fea + ((size_t)b * Cn) * Fn + f0;
    #pragma unroll
    for (int jj = 0; jj < 8; ++jj) {
      int l = jj * 256 + t;
      int c = l >> 5;
      int fi = (l & 31) << 2;
      float4 v = make_float4(0.f, 0.f, 0.f, 0.f);
      if (f0 + fi < Fn) v = *(const float4*)(fb + (size_t)c * Fn + fi);
      *(float4*)&a_s[c][fi] = v;
    }
  }
  __syncthreads();
  const int sg = t >> 6;
  const int fl = t & 63;
  float acc[2][16];
  #pragma unroll
  for (int j = 0; j < 2; j++)
    #pragma unroll
    for (int i = 0; i < 16; i++) acc[j][i] = 0.f;
  const int o0 = sg << 4;
  #pragma unroll 4
  for (int c = 0; c < 64; c++) {
    float4 w0 = *(float4*)&w_s[c][o0];
    float4 w1 = *(float4*)&w_s[c][o0 + 4];
    float4 w2 = *(float4*)&w_s[c][o0 + 8];
    float4 w3 = *(float4*)&w_s[c][o0 + 12];
    float2 av = *(float2*)&a_s[c][fl << 1];
    float wv[16] = {w0.x,w0.y,w0.z,w0.w, w1.x,w1.y,w1.z,w1.w,
                    w2.x,w2.y,w2.z,w2.w, w3.x,w3.y,w3.z,w3.w};
    #pragma unroll
    for (int i = 0; i < 16; i++) {
      acc[0][i] = fmaf(av.x, wv[i], acc[0][i]);
      acc[1][i] = fmaf(av.y, wv[i], acc[1][i]);
    }
  }
  u32* gdst = Gt + ((size_t)(b * 4 + sg) * Fn + f0 + (fl << 1)) * 8;
  #pragma unroll
  for (int j = 0; j < 2; j++) {
    int f = f0 + (fl << 1) + j;
    if (f < Fn) {
      uint4 u0, u1;
      u0.x = pack2(acc[j][0], acc[j][1]);   u0.y = pack2(acc[j][2], acc[j][3]);
      u0.z = pack2(acc[j][4], acc[j][5]);   u0.w = pack2(acc[j][6], acc[j][7]);
      u1.x = pack2(acc[j][8], acc[j][9]);   u1.y = pack2(acc[j][10], acc[j][11]);
      u1.z = pack2(acc[j][12], acc[j][13]); u1.w = pack2(acc[j][14], acc[j][15]);
      *(uint4*)(gdst + (size_t)j * 8) = u0;
      *(uint4*)(gdst + (size_t)j * 8 + 4) = u1;
    }
  }
}

// K2: block = (b,seg) x 128 faces. Thread = 1 face x 8 channels (half row).
// All 16 gathers issued as two 8-deep independent batches => high MLP.
// WRITE_BF16=1: y packed bf16 -> Y ws buffer. =0: y fp32 -> outF.
template<int WRITE_BF16>
__global__ __launch_bounds__(256) void k2_gather(
    const u32* __restrict__ Gt, const int* __restrict__ ring,
    const float* __restrict__ bias, u32* __restrict__ Y, float* __restrict__ outF,
    float* __restrict__ gsum, float* __restrict__ gsum2) {
  const int bid = blockIdx.x;
  const int combo = bid & 15;
  const int ft = bid >> 4;
  const int b = combo >> 2;
  const int seg = combo & 3;
  const int t = threadIdx.x;
  const int face_l = t >> 1;          // 0..127
  const int half = t & 1;
  const int fa = ft * 128 + face_l;
  const bool valid = fa < Fn;

  __shared__ float y_s[128][17];
  __shared__ float rs[16][17];
  __shared__ float rs2[16][17];

  float acc[8];
  #pragma unroll
  for (int i = 0; i < 8; i++) acc[i] = 0.f;

  const int c0 = seg * 16 + half * 8;
  float bv[8];
  #pragma unroll
  for (int i = 0; i < 8; i++) bv[i] = bias[c0 + i];

  if (valid) {
    const int4* rp = (const int4*)(ring + ((size_t)b * Fn + fa) * Kn);
    int4 i0 = rp[0], i1 = rp[1], i2 = rp[2], i3 = rp[3];
    int idx[16] = {i0.x,i0.y,i0.z,i0.w, i1.x,i1.y,i1.z,i1.w,
                   i2.x,i2.y,i2.z,i2.w, i3.x,i3.y,i3.z,i3.w};
    const uint4* Gs = (const uint4*)(Gt + (size_t)(b * 4 + seg) * Fn * 8);
    uint4 v[8], w[8];
    #pragma unroll
    for (int k = 0; k < 8; k++) v[k] = Gs[(size_t)idx[k] * 2 + half];
    #pragma unroll
    for (int k = 0; k < 8; k++) w[k] = Gs[(size_t)idx[8 + k] * 2 + half];
    #pragma unroll
    for (int k = 0; k < 8; k++) {
      u32 uu[4] = {v[k].x, v[k].y, v[k].z, v[k].w};
      #pragma unroll
      for (int p = 0; p < 4; p++) {
        acc[2*p]   += __uint_as_float(uu[p] << 16);
        acc[2*p+1] += __uint_as_float(uu[p] & 0xffff0000u);
      }
    }
    #pragma unroll
    for (int k = 0; k < 8; k++) {
      u32 uu[4] = {w[k].x, w[k].y, w[k].z, w[k].w};
      #pragma unroll
      for (int p = 0; p < 4; p++) {
        acc[2*p]   += __uint_as_float(uu[p] << 16);
        acc[2*p+1] += __uint_as_float(uu[p] & 0xffff0000u);
      }
    }
  }
  #pragma unroll
  for (int i = 0; i < 8; i++) acc[i] = valid ? acc[i] + bv[i] : 0.f;
  #pragma unroll
  for (int i = 0; i < 8; i++) y_s[face_l][half * 8 + i] = acc[i];
  __syncthreads();

  if (WRITE_BF16) {
    // 16 ch x 64 face-pairs = 1024 u32; 4 per thread
    const int fp = t & 63;             // face pair within tile
    const int chb = t >> 6;            // 0..3
    const int fa2 = ft * 64 + fp;      // u32 index within channel row
    if (fa2 * 2 < Fn) {                // Fn even => pair fully valid
      #pragma unroll
      for (int j = 0; j < 4; j++) {
        int ch = chb * 4 + j;
        u32 pv = pack2(y_s[fp * 2][ch], y_s[fp * 2 + 1][ch]);
        Y[((size_t)b * 64 + seg * 16 + ch) * (Fn / 2) + fa2] = pv;
      }
    }
  } else {
    const int fl2 = t & 127;
    const int chb = t >> 7;            // 0..1
    if (ft * 128 + fl2 < Fn) {
      float* ob = outF + ((size_t)b * 64 + seg * 16 + chb * 8) * Fn + ft * 128 + fl2;
      #pragma unroll
      for (int j = 0; j < 8; j++) ob[(size_t)j * Fn] = y_s[fl2][chb * 8 + j];
    }
  }

  {  // stats: 16 parts x 16 channels
    const int ch = t & 15, part = t >> 4;
    float s = 0.f, s2 = 0.f;
    #pragma unroll
    for (int i = 0; i < 8; i++) {
      float v = y_s[part * 8 + i][ch];
      s += v; s2 += v * v;
    }
    rs[part][ch] = s; rs2[part][ch] = s2;
  }
  __syncthreads();
  if (t < 16) {
    float s = 0.f;
    #pragma unroll
    for (int p = 0; p < 16; p++) s += rs[p][t];
    atomicAdd(&gsum[seg * 16 + t], s);
  } else if (t < 32) {
    const int ch = t - 16;
    float s2 = 0.f;
    #pragma unroll
    for (int p = 0; p < 16; p++) s2 += rs2[p][ch];
    atomicAdd(&gsum2[seg * 16 + ch], s2);
  }
}

__global__ void k3_stats(const float* __restrict__ gsum, const float* __restrict__ gsum2,
                         const float* __restrict__ gamma, const float* __restrict__ beta,
                         float* __restrict__ ab) {
  int o = threadIdx.x;
  if (o < 64) {
    float inv = 1.0f / (float)NTOT;
    float mean = gsum[o] * inv;
    float var = gsum2[o] * inv - mean * mean;  // biased
    float r = rsqrtf(var + EPS);
    float a = gamma[o] * r;
    ab[o] = a;
    ab[64 + o] = beta[o] - mean * a;
  }
}

// k4 (bf16 path): read packed-bf16 y (uint2 = 4 faces), write fp32 out (float4)
__global__ __launch_bounds__(256) void k4_norm_bf(const u32* __restrict__ Y,
                                                  const float* __restrict__ ab,
                                                  float* __restrict__ out) {
  int i = blockIdx.x * 256 + threadIdx.x;   // uint2 index; 3.2M total, exact cover
  int cglob = i / 12500;                    // b*64 + c   (12500 uint2 per channel)
  int c = cglob & 63;
  float a = ab[c], cc = ab[64 + c];
  uint2 u = ((const uint2*)Y)[i];
  float4 v;
  v.x = __uint_as_float(u.x << 16);
  v.y = __uint_as_float(u.x & 0xffff0000u);
  v.z = __uint_as_float(u.y << 16);
  v.w = __uint_as_float(u.y & 0xffff0000u);
  v.x = fmaxf(fmaf(v.x, a, cc), 0.f);
  v.y = fmaxf(fmaf(v.y, a, cc), 0.f);
  v.z = fmaxf(fmaf(v.z, a, cc), 0.f);
  v.w = fmaxf(fmaf(v.w, a, cc), 0.f);
  ((float4*)out)[i] = v;
}

// k4 (fallback): in-place fp32 normalize
__global__ __launch_bounds__(256) void k4_norm_f32(float* __restrict__ out,
                                                   const float* __restrict__ ab) {
  int i = blockIdx.x * 256 + threadIdx.x;   // float4 index
  int o = (i / (Fn / 4)) & 63;
  float a = ab[o], c = ab[64 + o];
  float4 v = ((float4*)out)[i];
  v.x = fmaxf(fmaf(v.x, a, c), 0.f);
  v.y = fmaxf(fmaf(v.y, a, c), 0.f);
  v.z = fmaxf(fmaf(v.z, a, c), 0.f);
  v.w = fmaxf(fmaf(v.w, a, c), 0.f);
  ((float4*)out)[i] = v;
}

extern "C" void kernel_launch(void* const* d_in, const int* in_sizes, int n_in,
                              void* d_out, int out_size, void* d_ws, size_t ws_size,
                              hipStream_t stream) {
  const float* fea   = (const float*)d_in[0];
  const int*   ring  = (const int*)d_in[1];
  const float* W     = (const float*)d_in[2];
  const float* bias  = (const float*)d_in[3];
  const float* gamma = (const float*)d_in[4];
  const float* beta  = (const float*)d_in[5];
  float* out = (float*)d_out;

  u32* Gt = (u32*)d_ws;                                   // 25.6 MB
  const size_t gtBytes = (size_t)Bn * 4 * Fn * 8 * 4;     // 25.6e6 B
  const size_t yBytes  = (size_t)Bn * 64 * (Fn / 2) * 4;  // 25.6e6 B
  const bool bf16y = ws_size >= gtBytes + yBytes + 1024;

  u32* Y = (u32*)((char*)d_ws + gtBytes);
  float* gsum  = bf16y ? (float*)((char*)d_ws + gtBytes + yBytes)
                       : (float*)((char*)d_ws + gtBytes);
  float* gsum2 = gsum + 64;
  float* ab    = gsum + 128;

  hipMemsetAsync(gsum, 0, 2 * 64 * sizeof(float), stream);
  k1_wgemm<<<dim3((Fn + 127) / 128, Bn), 256, 0, stream>>>(fea, W, Gt);
  const int ftiles = (Fn + 127) / 128;                    // 391
  if (bf16y) {
    k2_gather<1><<<dim3(ftiles * 16), 256, 0, stream>>>(Gt, ring, bias, Y, out, gsum, gsum2);
    k3_stats<<<1, 64, 0, stream>>>(gsum, gsum2, gamma, beta, ab);
    k4_norm_bf<<<dim3((Bn * 64 * (Fn / 2) / 2) / 256), 256, 0, stream>>>(Y, ab, out);
  } else {
    k2_gather<0><<<dim3(ftiles * 16), 256, 0, stream>>>(Gt, ring, bias, Y, out, gsum, gsum2);
    k3_stats<<<1, 64, 0, stream>>>(gsum, gsum2, gamma, beta, ab);
    k4_norm_f32<<<dim3((Bn * Cn * Fn / 4) / 256), 256, 0, stream>>>(out, ab);
  }
}